// Round 2
// baseline (232.663 us; speedup 1.0000x reference)
//
#include <hip/hip_runtime.h>
#include <stdint.h>

// CSSA: B=32, H=W=64, C=64, heads=4, hd=16, strip windows 64x8 -> 256 windows.
// Round 8: REVERT to round-6 structure (89 us: K natural + V^T in LDS,
// transposed QK^T so P feeds PV straight from registers, 16x16x16 MFMAs).
// ONE change: output store transpose. Round 6/7 stores had one 64B out line
// (token,head) covered by lanes {L,L+16,L+32,L+48} of a single store -> HW
// coalescer issues 4x16B partial-line writes -> RMW at L2/HBM: WRITE_SIZE
// measured 99-138 MB vs 33.5 MB ideal. Fix: 4x16 in-wave transpose via 4
// __shfl per tile so lanes 0-3 cover one full 64B line (adjacent lanes,
// contiguous bytes). Predict WRITE_SIZE -> ~34-50 MB, dur 89 -> ~75 us.
#define KSTR2 20    // K row: 16 ch + 4 pad (40 B)
#define VSTR  520   // Vt row: 512 tok + 8 pad

typedef __attribute__((ext_vector_type(4))) short          short4v;
typedef __attribute__((ext_vector_type(4))) float          f32x4;
typedef __attribute__((ext_vector_type(4))) unsigned short us4;
typedef __bf16 bf2_t __attribute__((ext_vector_type(2)));

__device__ __forceinline__ unsigned short f2bf(float f) {   // round-half-up
    union { float f; unsigned int u; } x; x.f = f;
    return (unsigned short)((x.u + 0x8000u) >> 16);
}
__device__ __forceinline__ float bf2f(unsigned short u) {
    union { unsigned int i; float f; } x; x.i = ((unsigned int)u) << 16; return x.f;
}
__device__ __forceinline__ unsigned int pk2bf(float lo, float hi) {
#if __has_builtin(__builtin_amdgcn_cvt_pk_bf16_f32)
    union { bf2_t v; unsigned int u; } c;
    c.v = __builtin_amdgcn_cvt_pk_bf16_f32(lo, hi);     // 1 VALU op
    return c.u;
#else
    union { float f; unsigned int u; } a, b; a.f = lo; b.f = hi;
    return __builtin_amdgcn_perm(b.u + 0x8000u, a.u + 0x8000u, 0x07060302u);
#endif
}
__device__ __forceinline__ short4v pk4bf(float a, float b, float c, float d) {
    union { short4v s; unsigned int u[2]; } p;
    p.u[0] = pk2bf(a, b);
    p.u[1] = pk2bf(c, d);
    return p.s;
}

__global__ __launch_bounds__(512, 6)
void CSSA_69355131896243_kernel(const float* __restrict__ qkv,
                                const float* __restrict__ wconv,
                                const float* __restrict__ bconv,
                                float* __restrict__ out)
{
    __shared__ unsigned short Kl[512 * KSTR2];   // 20480 B  K[token][d] bf16
    __shared__ unsigned short Vt[16 * VSTR];     // 16640 B  V^T[d][token] bf16
    __shared__ float Wl[144];                    // this head's 16x9 conv weights
    __shared__ float Bl[16];

    const int tid  = threadIdx.x;
    const int wave = tid >> 6, lane = tid & 63, quad = lane >> 4, l15 = lane & 15;

    // bid -> (window, head): head-siblings of a window are 8 apart -> same XCD
    // under round-robin dispatch -> shared Q/K/V/out lines merge in L2.
    const int bid = blockIdx.x;
    const int win = (bid & 7) * 32 + (bid >> 5);
    const int h   = (bid >> 3) & 3;
    const int b   = win >> 3, wx = win & 7;

    const size_t ONE  = (size_t)32 * 4096 * 64;
    const size_t base = ((size_t)b * 4096 + (size_t)wx * 8) * 64;
    const float* gQ = qkv + base;
    const float* gK = qkv + ONE + base;
    const float* gV = qkv + 2 * ONE + base;
    const int hc = h * 16;

    // ---- stage this head's K (natural) + V^T as bf16 ----
    {
        const int c4 = tid & 3;          // 4-ch group within head
        const int t0 = tid >> 2;         // 128 tokens per round
        #pragma unroll
        for (int r = 0; r < 4; ++r) {
            const int t = r * 128 + t0;
            const size_t goff = (size_t)(t >> 3) * 4096 + (size_t)(t & 7) * 64 + hc + c4 * 4;
            f32x4 kd = *(const f32x4*)(gK + goff);
            f32x4 vd = *(const f32x4*)(gV + goff);
            us4 kb;
            #pragma unroll
            for (int j = 0; j < 4; ++j) kb[j] = f2bf(kd[j]);
            *(us4*)(&Kl[t * KSTR2 + c4 * 4]) = kb;
            #pragma unroll
            for (int j = 0; j < 4; ++j) Vt[(c4 * 4 + j) * VSTR + t] = f2bf(vd[j]);
        }
    }
    if (tid < 144) Wl[tid] = wconv[h * 144 + tid];
    if (tid < 16)  Bl[tid] = bconv[hc + tid];

    // ---- Q prefetch + pack (independent of LDS -> overlaps barrier wait) ----
    const float SCL = 0.25f * 1.44269504088896341f;   // scale*log2(e) folded in
    const int q0 = wave * 64;
    short4v qf[4];   // B[k=d=quad*4+i][n=q=l15]
    #pragma unroll
    for (int t = 0; t < 4; ++t) {
        const int q = q0 + t * 16 + l15;
        f32x4 qv = *(const f32x4*)(gQ + (size_t)(q >> 3) * 4096 + (size_t)(q & 7) * 64 + hc + quad * 4);
        qf[t] = pk4bf(qv[0] * SCL, qv[1] * SCL, qv[2] * SCL, qv[3] * SCL);
    }
    __syncthreads();

    f32x4 acc[4];
    float lp[4];
    #pragma unroll
    for (int t = 0; t < 4; ++t) { acc[t] = (f32x4)0.0f; lp[t] = 0.0f; }

    // ---- main loop: 32 chunks x 16 keys, all frags from LDS (imm offsets) ----
    #pragma unroll 4
    for (int c = 0; c < 32; ++c) {
        // K A-frag: A[m=key=l15][k=d=quad*4+i]
        const short4v kf = *(const short4v*)(&Kl[(c * 16 + l15) * KSTR2 + quad * 4]);
        // V A-frag for PV: A[m=d=l15][k=key=quad*4+i]
        const short4v vf = *(const short4v*)(&Vt[l15 * VSTR + c * 16 + quad * 4]);
        #pragma unroll
        for (int t = 0; t < 4; ++t) {
            // s^T[key][q]: C row=quad*4+j -> key, col=l15 -> q
            f32x4 s = __builtin_amdgcn_mfma_f32_16x16x16bf16_1k(kf, qf[t], (f32x4)0.0f, 0, 0, 0);
            const float p0 = __builtin_amdgcn_exp2f(s[0]);
            const float p1 = __builtin_amdgcn_exp2f(s[1]);
            const float p2 = __builtin_amdgcn_exp2f(s[2]);
            const float p3 = __builtin_amdgcn_exp2f(s[3]);
            lp[t] += (p0 + p1) + (p2 + p3);
            // P C-layout == K=16 B-frag layout -> PV straight from registers
            acc[t] = __builtin_amdgcn_mfma_f32_16x16x16bf16_1k(vf, pk4bf(p0, p1, p2, p3), acc[t], 0, 0, 0);
        }
    }

    // ---- denominators: cross-quad reduce ----
    float linv[4];
    #pragma unroll
    for (int t = 0; t < 4; ++t) {
        float v = lp[t];
        v += __shfl_xor(v, 16, 64);
        v += __shfl_xor(v, 32, 64);
        linv[t] = __builtin_amdgcn_rcpf(v);
    }

    // ---- epilogue: LePE from resident V^T, normalize ----
    #pragma unroll
    for (int j = 0; j < 4; ++j) {
        const int d = quad * 4 + j;
        float w9[9];
        #pragma unroll
        for (int o = 0; o < 9; ++o) w9[o] = Wl[d * 9 + o];
        const float bs = Bl[d];
        #pragma unroll
        for (int t = 0; t < 4; ++t) {
            const int q = q0 + t * 16 + l15;
            const int y = q >> 3, x = q & 7;
            float lep = bs;
            #pragma unroll
            for (int dy = 0; dy < 3; ++dy) {
                #pragma unroll
                for (int dx = 0; dx < 3; ++dx) {
                    const int yy = y + dy - 1, xx = x + dx - 1;
                    const bool ok = ((unsigned)yy < 64u) && ((unsigned)xx < 8u);
                    const int tt = (q + (dy - 1) * 8 + (dx - 1)) & 511;   // masked if OOB
                    lep += (ok ? w9[dy * 3 + dx] : 0.0f) * bf2f(Vt[d * VSTR + tt]);
                }
            }
            acc[t][j] = acc[t][j] * linv[t] + lep;
        }
    }

    // ---- store: 4x16 in-wave transpose so lanes 0-3 write one FULL 64B line.
    // src lane (quad'=L&3, l15'=L>>2) holds d-chunk (L&3) of token (L>>2);
    // after shfl, lane L writes 16B at token(L>>2)*256B + h*64 + (L&3)*16B ->
    // adjacent lanes contiguous -> coalescer emits full-line writes (no RMW).
    float* gO = out + base;
    #pragma unroll
    for (int t = 0; t < 4; ++t) {
        const int src = (lane & 3) * 16 + (lane >> 2);
        f32x4 o;
        #pragma unroll
        for (int j = 0; j < 4; ++j) o[j] = __shfl(acc[t][j], src, 64);
        const int tok = q0 + t * 16 + (lane >> 2);
        *(f32x4*)(gO + (size_t)(tok >> 3) * 4096 + (size_t)(tok & 7) * 64 + hc + (lane & 3) * 4) = o;
    }
}

extern "C" void kernel_launch(void* const* d_in, const int* in_sizes, int n_in,
                              void* d_out, int out_size, void* d_ws, size_t ws_size,
                              hipStream_t stream) {
    const float* qkv   = (const float*)d_in[0];
    const float* wconv = (const float*)d_in[1];
    const float* bconv = (const float*)d_in[2];
    float* outp = (float*)d_out;
    hipLaunchKernelGGL(CSSA_69355131896243_kernel, dim3(1024), dim3(512), 0, stream,
                       qkv, wconv, bconv, outp);
}

// Round 3
// 215.717 us; speedup vs baseline: 1.0786x; 1.0786x over previous
//
#include <hip/hip_runtime.h>
#include <stdint.h>

// CSSA: B=32, H=W=64, C=64, heads=4, hd=16, strip windows 64x8 -> 256 windows.
// Round 9: fuse ALL 4 HEADS into one block. Block = window: 256 blocks (1:1
// with CUs, no tail), 1024 thr = 16 waves; wave w -> head w&3, q-rows
// (w>>2)*128..+127 (8 tiles). K[512][64] + V^T[64][512] for the whole window
// staged once in LDS (138.8 KB). Rationale (r8 post-mortem): WRITE_SIZE was
// 3-5x ideal because each 256B output record is written by 4 DIFFERENT blocks
// (one per head) -> partial-dirty L2 lines RMW-churn to HBM. One block now
// owns every output line it touches (and every input line it reads): predict
// WRITE 99->~35 MB, FETCH ~85-100 MB, dur 89 -> ~60-70 us.
// QK^T computed transposed (A=K,B=Q) so P's C-layout == K=16 B-frag layout:
// PV MFMA consumes P straight from registers (r6 structure, kept).
#define KSTR 68     // K row: 64 ch + 4 pad (136 B, 8B-aligned for b64 frags)
#define VSTR 520    // Vt row: 512 tok + 8 pad

typedef __attribute__((ext_vector_type(4))) short          short4v;
typedef __attribute__((ext_vector_type(4))) float          f32x4;
typedef __attribute__((ext_vector_type(4))) unsigned short us4;
typedef __bf16 bf2_t __attribute__((ext_vector_type(2)));

__device__ __forceinline__ float bf2f(unsigned short u) {
    union { unsigned int i; float f; } x; x.i = ((unsigned int)u) << 16; return x.f;
}
__device__ __forceinline__ unsigned int pk2bf(float lo, float hi) {
#if __has_builtin(__builtin_amdgcn_cvt_pk_bf16_f32)
    union { bf2_t v; unsigned int u; } c;
    c.v = __builtin_amdgcn_cvt_pk_bf16_f32(lo, hi);     // 1 VALU op
    return c.u;
#else
    union { float f; unsigned int u; } a, b; a.f = lo; b.f = hi;
    return __builtin_amdgcn_perm(b.u + 0x8000u, a.u + 0x8000u, 0x07060302u);
#endif
}
__device__ __forceinline__ short4v pk4bf(float a, float b, float c, float d) {
    union { short4v s; unsigned int u[2]; } p;
    p.u[0] = pk2bf(a, b);
    p.u[1] = pk2bf(c, d);
    return p.s;
}

__global__ __launch_bounds__(1024, 4)
void CSSA_69355131896243_kernel(const float* __restrict__ qkv,
                                const float* __restrict__ wconv,
                                const float* __restrict__ bconv,
                                float* __restrict__ out)
{
    __shared__ unsigned short Kl[512 * KSTR];   // 69632 B  K[token][ch] bf16
    __shared__ unsigned short Vt[64 * VSTR];    // 66560 B  V^T[ch][token] bf16
    __shared__ float Wl[576];                   // all 64 ch x 9 conv weights
    __shared__ float Bl[64];

    const int tid  = threadIdx.x;
    const int wave = tid >> 6, lane = tid & 63, quad = lane >> 4, l15 = lane & 15;

    // block = window; no cross-block data sharing remains -> no swizzle needed
    const int bid = blockIdx.x;
    const int b = bid >> 3, wx = bid & 7;

    const size_t ONE  = (size_t)32 * 4096 * 64;
    const size_t base = ((size_t)b * 4096 + (size_t)wx * 8) * 64;
    const float* gQ = qkv + base;
    const float* gK = qkv + ONE + base;
    const float* gV = qkv + 2 * ONE + base;

    // ---- stage K (natural) + V^T as bf16, all 64 channels ----
    {
        const int c16 = tid & 15;        // 4-ch group (0..15) -> ch c16*4..+3
        const int t0  = tid >> 4;        // 64 tokens per round
        #pragma unroll
        for (int r = 0; r < 8; ++r) {
            const int t = r * 64 + t0;
            const size_t goff = (size_t)(t >> 3) * 4096 + (size_t)(t & 7) * 64 + c16 * 4;
            f32x4 kd = *(const f32x4*)(gK + goff);
            f32x4 vd = *(const f32x4*)(gV + goff);
            union { us4 v; unsigned int u[2]; } kb;
            kb.u[0] = pk2bf(kd[0], kd[1]);
            kb.u[1] = pk2bf(kd[2], kd[3]);
            *(us4*)(&Kl[t * KSTR + c16 * 4]) = kb.v;
            const unsigned int v01 = pk2bf(vd[0], vd[1]);
            const unsigned int v23 = pk2bf(vd[2], vd[3]);
            Vt[(c16 * 4 + 0) * VSTR + t] = (unsigned short)(v01 & 0xffffu);
            Vt[(c16 * 4 + 1) * VSTR + t] = (unsigned short)(v01 >> 16);
            Vt[(c16 * 4 + 2) * VSTR + t] = (unsigned short)(v23 & 0xffffu);
            Vt[(c16 * 4 + 3) * VSTR + t] = (unsigned short)(v23 >> 16);
        }
    }
    if (tid < 576) Wl[tid] = wconv[tid];
    if (tid < 64)  Bl[tid] = bconv[tid];

    // ---- Q prefetch + pack (independent of LDS -> overlaps barrier wait) ----
    const float SCL = 0.25f * 1.44269504088896341f;   // scale*log2(e) folded in
    const int h  = wave & 3, hc = h * 16;
    const int q0 = (wave >> 2) * 128;
    short4v qf[8];   // B[k=d=quad*4+i][n=q=l15]
    #pragma unroll
    for (int t = 0; t < 8; ++t) {
        const int q = q0 + t * 16 + l15;
        f32x4 qv = *(const f32x4*)(gQ + (size_t)(q >> 3) * 4096 + (size_t)(q & 7) * 64 + hc + quad * 4);
        qf[t] = pk4bf(qv[0] * SCL, qv[1] * SCL, qv[2] * SCL, qv[3] * SCL);
    }
    __syncthreads();

    f32x4 acc[8];
    float lp[8];
    #pragma unroll
    for (int t = 0; t < 8; ++t) { acc[t] = (f32x4)0.0f; lp[t] = 0.0f; }

    // ---- main loop: 32 chunks x 16 keys, frags from LDS (imm offsets) ----
    #pragma unroll 2
    for (int c = 0; c < 32; ++c) {
        // K A-frag: A[m=key=l15][k=d=quad*4+i] for this head
        const short4v kf = *(const short4v*)(&Kl[(c * 16 + l15) * KSTR + hc + quad * 4]);
        // V A-frag for PV: A[m=d=l15][k=key=quad*4+i]
        const short4v vf = *(const short4v*)(&Vt[(hc + l15) * VSTR + c * 16 + quad * 4]);
        #pragma unroll
        for (int t = 0; t < 8; ++t) {
            // s^T[key][q]: C row=quad*4+j -> key, col=l15 -> q
            f32x4 s = __builtin_amdgcn_mfma_f32_16x16x16bf16_1k(kf, qf[t], (f32x4)0.0f, 0, 0, 0);
            const float p0 = __builtin_amdgcn_exp2f(s[0]);
            const float p1 = __builtin_amdgcn_exp2f(s[1]);
            const float p2 = __builtin_amdgcn_exp2f(s[2]);
            const float p3 = __builtin_amdgcn_exp2f(s[3]);
            lp[t] += (p0 + p1) + (p2 + p3);
            // P C-layout == K=16 B-frag layout -> PV straight from registers
            acc[t] = __builtin_amdgcn_mfma_f32_16x16x16bf16_1k(vf, pk4bf(p0, p1, p2, p3), acc[t], 0, 0, 0);
        }
    }

    // ---- denominators: cross-quad reduce ----
    float linv[8];
    #pragma unroll
    for (int t = 0; t < 8; ++t) {
        float v = lp[t];
        v += __shfl_xor(v, 16, 64);
        v += __shfl_xor(v, 32, 64);
        linv[t] = __builtin_amdgcn_rcpf(v);
    }

    // ---- epilogue: LePE from resident V^T, normalize, f32x4 stores ----
    #pragma unroll
    for (int j = 0; j < 4; ++j) {
        const int d = hc + quad * 4 + j;
        float w9[9];
        #pragma unroll
        for (int o = 0; o < 9; ++o) w9[o] = Wl[d * 9 + o];
        const float bs = Bl[d];
        const unsigned short* vrow = &Vt[d * VSTR];
        #pragma unroll
        for (int t = 0; t < 8; ++t) {
            const int q = q0 + t * 16 + l15;
            const int y = q >> 3, x = q & 7;
            float lep = bs;
            #pragma unroll
            for (int dy = 0; dy < 3; ++dy) {
                #pragma unroll
                for (int dx = 0; dx < 3; ++dx) {
                    const int yy = y + dy - 1, xx = x + dx - 1;
                    const bool ok = ((unsigned)yy < 64u) && ((unsigned)xx < 8u);
                    const int tt = (q + (dy - 1) * 8 + (dx - 1)) & 511;   // masked if OOB
                    lep += (ok ? w9[dy * 3 + dx] : 0.0f) * bf2f(vrow[tt]);
                }
            }
            acc[t][j] = acc[t][j] * linv[t] + lep;
        }
    }
    float* gO = out + base;
    #pragma unroll
    for (int t = 0; t < 8; ++t) {
        const int q = q0 + t * 16 + l15;
        *(f32x4*)(gO + (size_t)(q >> 3) * 4096 + (size_t)(q & 7) * 64 + hc + quad * 4) = acc[t];
    }
}

extern "C" void kernel_launch(void* const* d_in, const int* in_sizes, int n_in,
                              void* d_out, int out_size, void* d_ws, size_t ws_size,
                              hipStream_t stream) {
    const float* qkv   = (const float*)d_in[0];
    const float* wconv = (const float*)d_in[1];
    const float* bconv = (const float*)d_in[2];
    float* outp = (float*)d_out;
    hipLaunchKernelGGL(CSSA_69355131896243_kernel, dim3(256), dim3(1024), 0, stream,
                       qkv, wconv, bconv, outp);
}